// Round 12
// baseline (151.107 us; speedup 1.0000x reference)
//
#include <hip/hip_runtime.h>

// Fused deformable-conv net — frozen r7/r10 structure (69 us, 92% VALUBusy)
// with two VALU-pipe cuts:
//  1. FC c-outer + bias-by-784-elements so all 8 per-channel loads use
//     13-bit signed imm offsets (o*784-3136 in [-3136,2352]B); kills ~160
//     per-load 64-bit v_add pairs from the old o-outer c*6272B offsets.
//  2. Bilinear gather addresses via v_fma_f32 (addr=(int)fma(qx,30,qy),
//     exact: max 899 < 2^24) instead of int mul/add chains.
// Frozen per r2-r10 evidence: 256-thr block, one image/block, if(tid<196),
// k-outer/p-inner acc[4][8], direct xs[int] indexing, LDS weights, no
// launch-bounds min-waves, no atomics, shuffle+LDS reduce, scalar fp32
// (v_pk_* is 2-pass on gfx950 — density only).
// (Resubmission of round 11 — container infra failure, theory untested.)

#define HH 28
#define WW 28
#define WP 30
#define NPOS 784
#define NPOOL 1568
#define CELLS 196

__global__ __launch_bounds__(256) void deform_net_kernel(
    const float* __restrict__ x,       // (B,1,28,28)
    const float* __restrict__ w_off,   // (18,1,3,3)
    const float* __restrict__ b_off,   // (18,)
    const float* __restrict__ w_conv,  // (8,1,3,3)
    const float* __restrict__ w_fc,    // (10,1568)
    const float* __restrict__ b_fc,    // (10,)
    float* __restrict__ out)           // (B,10)
{
    __shared__ float xs[900];          // padded image
    __shared__ float wo_s[162];        // w_off
    __shared__ float bo_s[18];         // b_off
    __shared__ float wc_s[72];         // w_conv
    __shared__ float red[4][10];

    const int b   = blockIdx.x;
    const int tid = threadIdx.x;

    if (tid < 162) wo_s[tid] = w_off[tid];
    if (tid < 18)  bo_s[tid] = b_off[tid];
    if (tid < 72)  wc_s[tid] = w_conv[tid];

    // Stage zero-padded image into LDS.
    const float* xb = x + (size_t)b * NPOS;
    for (int i = tid; i < 900; i += 256) {
        int r = i / WP, c = i % WP;
        float v = 0.f;
        if (r >= 1 && r <= HH && c >= 1 && c <= WW)
            v = xb[(r - 1) * WW + (c - 1)];
        xs[i] = v;
    }
    __syncthreads();

    float fc[10];
    #pragma unroll
    for (int c = 0; c < 10; c++) fc[c] = 0.f;

    if (tid < CELLS) {
        const int ph = tid / 14, pw = tid % 14;   // pool cell coords
        const int h0 = 2 * ph, w0 = 2 * pw;       // top-left output position

        // 4x4 padded-image neighborhood covering all 4 positions' 3x3 taps.
        float nb[16];
        #pragma unroll
        for (int i = 0; i < 4; i++)
            #pragma unroll
            for (int j = 0; j < 4; j++)
                nb[i * 4 + j] = xs[(h0 + i) * WP + (w0 + j)];

        float acc[4][8];
        #pragma unroll
        for (int p = 0; p < 4; p++)
            #pragma unroll
            for (int o = 0; o < 8; o++) acc[p][o] = 0.f;

        #pragma unroll
        for (int k = 0; k < 9; k++) {          // deform tap
            const int kx = k / 3, ky = k % 3;
            #pragma unroll
            for (int p = 0; p < 4; p++) {      // position within pool cell
                const int dh = p >> 1, dw = p & 1;

                // offset channels k (x) and k+9 (y): 3x3 conv at (h0+dh, w0+dw)
                float offx = bo_s[k], offy = bo_s[k + 9];
                #pragma unroll
                for (int t = 0; t < 9; t++) {
                    float nv = nb[(dh + t / 3) * 4 + (dw + t % 3)];
                    offx = fmaf(wo_s[k * 9 + t],       nv, offx);
                    offy = fmaf(wo_s[(k + 9) * 9 + t], nv, offy);
                }

                // sample coords in padded frame: p0=(h+1,w+1), pn=(kx-1,ky-1)
                float p_x = (float)(h0 + dh + kx) + offx;
                float p_y = (float)(w0 + dw + ky) + offy;

                float q0x = floorf(p_x), q0y = floorf(p_y);
                float qltx = fminf(fmaxf(q0x,       0.f), 29.f);
                float qlty = fminf(fmaxf(q0y,       0.f), 29.f);
                float qrbx = fminf(fmaxf(q0x + 1.f, 0.f), 29.f);
                float qrby = fminf(fmaxf(q0y + 1.f, 0.f), 29.f);
                float px   = fminf(fmaxf(p_x,       0.f), 29.f);
                float py   = fminf(fmaxf(p_y,       0.f), 29.f);

                float gltx = 1.f + (qltx - px);
                float glty = 1.f + (qlty - py);
                float grbx = 1.f - (qrbx - px);
                float grby = 1.f - (qrby - py);

                // float-side address formation (exact: <= 899)
                float a_lt = fmaf(qltx, 30.f, qlty);
                float a_lb = fmaf(qltx, 30.f, qrby);
                float a_rt = fmaf(qrbx, 30.f, qlty);
                float a_rb = fmaf(qrbx, 30.f, qrby);

                float xlt = xs[(int)a_lt];
                float xlb = xs[(int)a_lb];
                float xrt = xs[(int)a_rt];
                float xrb = xs[(int)a_rb];

                // factored bilinear combine (same clip semantics)
                float s = gltx * (glty * xlt + grby * xlb)
                        + grbx * (glty * xrt + grby * xrb);

                #pragma unroll
                for (int o = 0; o < 8; o++)
                    acc[p][o] = fmaf(wc_s[o * 9 + k], s, acc[p][o]);
            }
        }

        // relu + 2x2 maxpool in registers.
        float m[8];
        #pragma unroll
        for (int o = 0; o < 8; o++)
            m[o] = fmaxf(fmaxf(fmaxf(acc[0][o], acc[1][o]),
                               fmaxf(acc[2][o], acc[3][o])), 0.f);

        // FC partials, c-outer, biased base so o-offsets fit 13-bit imm:
        // wr[o*196 - 784] -> byte offsets o*784-3136 in [-3136, +2352].
        #pragma unroll
        for (int c = 0; c < 10; c++) {
            const float* wr = w_fc + c * NPOOL + tid + 784;
            float a = fc[c];
            #pragma unroll
            for (int o = 0; o < 8; o++)
                a = fmaf(m[o], wr[o * CELLS - 784], a);
            fc[c] = a;
        }
    }

    // Wave (64-lane) shuffle reduce, then cross-wave via LDS.
    #pragma unroll
    for (int c = 0; c < 10; c++) {
        #pragma unroll
        for (int sh = 32; sh > 0; sh >>= 1)
            fc[c] += __shfl_down(fc[c], sh, 64);
    }
    const int wave = tid >> 6, lane = tid & 63;
    if (lane == 0) {
        #pragma unroll
        for (int c = 0; c < 10; c++) red[wave][c] = fc[c];
    }
    __syncthreads();
    if (tid < 10)
        out[b * 10 + tid] = red[0][tid] + red[1][tid] + red[2][tid]
                          + red[3][tid] + b_fc[tid];
}

extern "C" void kernel_launch(void* const* d_in, const int* in_sizes, int n_in,
                              void* d_out, int out_size, void* d_ws, size_t ws_size,
                              hipStream_t stream) {
    const float* x      = (const float*)d_in[0];
    const float* w_off  = (const float*)d_in[1];
    const float* b_off  = (const float*)d_in[2];
    const float* w_conv = (const float*)d_in[3];
    const float* w_fc   = (const float*)d_in[4];
    const float* b_fc   = (const float*)d_in[5];
    float* out = (float*)d_out;

    const int B = in_sizes[0] / NPOS;
    deform_net_kernel<<<B, 256, 0, stream>>>(x, w_off, b_off, w_conv, w_fc, b_fc, out);
}

// Round 13
// 125.964 us; speedup vs baseline: 1.1996x; 1.1996x over previous
//
#include <hip/hip_runtime.h>

// Fused deformable-conv net — exact r10 champion (68.6 us best, 64 VGPR,
// 92% VALUBusy) with ONE register-neutral change: explicit v_med3_f32
// clamps (__builtin_amdgcn_fmed3f) replacing fminf(fmaxf()) pairs —
// 6 -> 3+3 ops per (k,p) if the backend peephole wasn't already firing.
// All inputs to med3 are finite (no NaN-semantics difference).
// Frozen per r2-r12 evidence: 256-thr block, one image/block, if(tid<196),
// k-outer/p-inner acc[4][8], direct xs[int] indexing, LDS weights,
// o-outer FC with wrow pointers, no launch-bounds min-waves, no atomics,
// shuffle+LDS reduce, scalar fp32 only. r12's c-outer FC (+10 live base
// pointers -> 88 VGPR, 60% busy) and float-addr gather are reverted.

#define HH 28
#define WW 28
#define WP 30
#define NPOS 784
#define NPOOL 1568
#define CELLS 196

__global__ __launch_bounds__(256) void deform_net_kernel(
    const float* __restrict__ x,       // (B,1,28,28)
    const float* __restrict__ w_off,   // (18,1,3,3)
    const float* __restrict__ b_off,   // (18,)
    const float* __restrict__ w_conv,  // (8,1,3,3)
    const float* __restrict__ w_fc,    // (10,1568)
    const float* __restrict__ b_fc,    // (10,)
    float* __restrict__ out)           // (B,10)
{
    __shared__ float xs[900];          // padded image
    __shared__ float wo_s[162];        // w_off
    __shared__ float bo_s[18];         // b_off
    __shared__ float wc_s[72];         // w_conv
    __shared__ float red[4][10];

    const int b   = blockIdx.x;
    const int tid = threadIdx.x;

    if (tid < 162) wo_s[tid] = w_off[tid];
    if (tid < 18)  bo_s[tid] = b_off[tid];
    if (tid < 72)  wc_s[tid] = w_conv[tid];

    // Stage zero-padded image into LDS.
    const float* xb = x + (size_t)b * NPOS;
    for (int i = tid; i < 900; i += 256) {
        int r = i / WP, c = i % WP;
        float v = 0.f;
        if (r >= 1 && r <= HH && c >= 1 && c <= WW)
            v = xb[(r - 1) * WW + (c - 1)];
        xs[i] = v;
    }
    __syncthreads();

    float fc[10];
    #pragma unroll
    for (int c = 0; c < 10; c++) fc[c] = 0.f;

    if (tid < CELLS) {
        const int ph = tid / 14, pw = tid % 14;   // pool cell coords
        const int h0 = 2 * ph, w0 = 2 * pw;       // top-left output position

        // 4x4 padded-image neighborhood covering all 4 positions' 3x3 taps.
        float nb[16];
        #pragma unroll
        for (int i = 0; i < 4; i++)
            #pragma unroll
            for (int j = 0; j < 4; j++)
                nb[i * 4 + j] = xs[(h0 + i) * WP + (w0 + j)];

        float acc[4][8];
        #pragma unroll
        for (int p = 0; p < 4; p++)
            #pragma unroll
            for (int o = 0; o < 8; o++) acc[p][o] = 0.f;

        #pragma unroll
        for (int k = 0; k < 9; k++) {          // deform tap
            const int kx = k / 3, ky = k % 3;
            #pragma unroll
            for (int p = 0; p < 4; p++) {      // position within pool cell
                const int dh = p >> 1, dw = p & 1;

                // offset channels k (x) and k+9 (y): 3x3 conv at (h0+dh, w0+dw)
                float offx = bo_s[k], offy = bo_s[k + 9];
                #pragma unroll
                for (int t = 0; t < 9; t++) {
                    float nv = nb[(dh + t / 3) * 4 + (dw + t % 3)];
                    offx = fmaf(wo_s[k * 9 + t],       nv, offx);
                    offy = fmaf(wo_s[(k + 9) * 9 + t], nv, offy);
                }

                // sample coords in padded frame: p0=(h+1,w+1), pn=(kx-1,ky-1)
                float p_x = (float)(h0 + dh + kx) + offx;
                float p_y = (float)(w0 + dw + ky) + offy;

                float q0x = floorf(p_x), q0y = floorf(p_y);
                float qltx = __builtin_amdgcn_fmed3f(q0x,       0.f, 29.f);
                float qlty = __builtin_amdgcn_fmed3f(q0y,       0.f, 29.f);
                float qrbx = __builtin_amdgcn_fmed3f(q0x + 1.f, 0.f, 29.f);
                float qrby = __builtin_amdgcn_fmed3f(q0y + 1.f, 0.f, 29.f);
                float px   = __builtin_amdgcn_fmed3f(p_x,       0.f, 29.f);
                float py   = __builtin_amdgcn_fmed3f(p_y,       0.f, 29.f);

                float gltx = 1.f + (qltx - px);
                float glty = 1.f + (qlty - py);
                float grbx = 1.f - (qrbx - px);
                float grby = 1.f - (qrby - py);

                int ilx = (int)qltx, ily = (int)qlty;
                int irx = (int)qrbx, iry = (int)qrby;

                float xlt = xs[ilx * WP + ily];
                float xrb = xs[irx * WP + iry];
                float xlb = xs[ilx * WP + iry];
                float xrt = xs[irx * WP + ily];

                // factored bilinear combine (same clip semantics)
                float s = gltx * (glty * xlt + grby * xlb)
                        + grbx * (glty * xrt + grby * xrb);

                #pragma unroll
                for (int o = 0; o < 8; o++)
                    acc[p][o] = fmaf(wc_s[o * 9 + k], s, acc[p][o]);
            }
        }

        // relu + 2x2 maxpool in registers, then FC partial sums (o-outer).
        #pragma unroll
        for (int o = 0; o < 8; o++) {
            float m = fmaxf(fmaxf(acc[0][o], acc[1][o]),
                            fmaxf(acc[2][o], acc[3][o]));
            m = fmaxf(m, 0.f);
            const float* wrow = w_fc + o * CELLS + tid;  // flat idx o*196+cell
            #pragma unroll
            for (int c = 0; c < 10; c++)
                fc[c] = fmaf(m, wrow[c * NPOOL], fc[c]);
        }
    }

    // Wave (64-lane) shuffle reduce, then cross-wave via LDS.
    #pragma unroll
    for (int c = 0; c < 10; c++) {
        #pragma unroll
        for (int sh = 32; sh > 0; sh >>= 1)
            fc[c] += __shfl_down(fc[c], sh, 64);
    }
    const int wave = tid >> 6, lane = tid & 63;
    if (lane == 0) {
        #pragma unroll
        for (int c = 0; c < 10; c++) red[wave][c] = fc[c];
    }
    __syncthreads();
    if (tid < 10)
        out[b * 10 + tid] = red[0][tid] + red[1][tid] + red[2][tid]
                          + red[3][tid] + b_fc[tid];
}

extern "C" void kernel_launch(void* const* d_in, const int* in_sizes, int n_in,
                              void* d_out, int out_size, void* d_ws, size_t ws_size,
                              hipStream_t stream) {
    const float* x      = (const float*)d_in[0];
    const float* w_off  = (const float*)d_in[1];
    const float* b_off  = (const float*)d_in[2];
    const float* w_conv = (const float*)d_in[3];
    const float* w_fc   = (const float*)d_in[4];
    const float* b_fc   = (const float*)d_in[5];
    float* out = (float*)d_out;

    const int B = in_sizes[0] / NPOS;
    deform_net_kernel<<<B, 256, 0, stream>>>(x, w_off, b_off, w_conv, w_fc, b_fc, out);
}